// Round 1
// baseline (25.146 us; speedup 1.0000x reference)
//
#include <hip/hip_runtime.h>

#define BATCH 256
#define SEQ   512
#define DIM   64
#define VOC   100
#define NTHREADS 512
#define ENC_PITCH 68   // floats; 272B rows, 16B-aligned, breaks pow2 bank stride

__global__ __launch_bounds__(NTHREADS)
void ncoe_kernel(const int* __restrict__ src_ids,
                 const int* __restrict__ dst_ids,
                 const float* __restrict__ W1,
                 const float* __restrict__ b1,
                 const float* __restrict__ W2,
                 const float* __restrict__ b2,
                 float* __restrict__ out)
{
    __shared__ __align__(16) float sW2[DIM][DIM];      // [in][out], 16 KB
    __shared__ __align__(16) float sW1[2][DIM];
    __shared__ __align__(16) float sb1[DIM];
    __shared__ __align__(16) float sb2[DIM];
    __shared__ __align__(16) float enc[VOC][ENC_PITCH]; // 27.2 KB
    __shared__ int hist_s[104];
    __shared__ int hist_d[104];

    const int t   = threadIdx.x;
    const int row = blockIdx.x;

    // ---- zero histograms + stage weights into LDS ----
    if (t < 104) { hist_s[t] = 0; hist_d[t] = 0; }
    {
        const float4* W2v  = (const float4*)W2;        // 1024 float4
        float4*       sW2v = (float4*)&sW2[0][0];
        sW2v[t]       = W2v[t];
        sW2v[t + 512] = W2v[t + 512];
        if (t < 32)      ((float4*)&sW1[0][0])[t] = ((const float4*)W1)[t];
        else if (t < 48) ((float4*)sb1)[t - 32]   = ((const float4*)b1)[t - 32];
        else if (t < 64) ((float4*)sb2)[t - 48]   = ((const float4*)b2)[t - 48];
    }
    __syncthreads();

    // ---- per-row histograms (one id per thread, S == NTHREADS) ----
    {
        int a = src_ids[row * SEQ + t];
        int b = dst_ids[row * SEQ + t];
        atomicAdd(&hist_s[a], 1);
        atomicAdd(&hist_d[b], 1);
    }
    __syncthreads();

    // ---- per-(row, vocab) MLP: enc[v][o] = relu(x@W1+b1)@W2 + b2 ----
    // 25 v-tiles x 16 o-tiles = 400 active threads, 4x4 register tile each.
    if (t < 400) {
        const int tv = t >> 4;        // 0..24
        const int to = t & 15;        // 0..15
        const int vbase = tv * 4;
        const int obase = to * 4;

        float av[4], bv[4];
        #pragma unroll
        for (int r = 0; r < 4; ++r) {
            int v = vbase + r;
            // id 0 is padding: features forced to zero (mask), then encoded
            av[r] = (v == 0) ? 0.f : (float)hist_s[v];
            bv[r] = (v == 0) ? 0.f : (float)hist_d[v];
        }

        float acc[4][4];
        #pragma unroll
        for (int r = 0; r < 4; ++r)
            #pragma unroll
            for (int c = 0; c < 4; ++c)
                acc[r][c] = sb2[obase + c];

        #pragma unroll 8
        for (int d = 0; d < DIM; ++d) {
            float w10 = sW1[0][d];   // wave-uniform -> LDS broadcast
            float w11 = sW1[1][d];
            float bb  = sb1[d];
            float4 w2 = *(const float4*)&sW2[d][obase];
            #pragma unroll
            for (int r = 0; r < 4; ++r) {
                float h = fmaxf(0.f, fmaf(av[r], w10, fmaf(bv[r], w11, bb)));
                acc[r][0] = fmaf(h, w2.x, acc[r][0]);
                acc[r][1] = fmaf(h, w2.y, acc[r][1]);
                acc[r][2] = fmaf(h, w2.z, acc[r][2]);
                acc[r][3] = fmaf(h, w2.w, acc[r][3]);
            }
        }

        #pragma unroll
        for (int r = 0; r < 4; ++r) {
            float4 res = make_float4(acc[r][0], acc[r][1], acc[r][2], acc[r][3]);
            *(float4*)&enc[vbase + r][obase] = res;
        }
    }
    __syncthreads();

    // ---- gather: out[row, j, :] = enc[id[row, j]][:], float4 stores ----
    float4* out4 = (float4*)out;
    const size_t rowOff = (size_t)row * (SEQ * DIM / 4);
    const size_t dstOff = (size_t)BATCH * (size_t)(SEQ * DIM / 4);
    #pragma unroll
    for (int k = 0; k < (SEQ * DIM / 4) / NTHREADS; ++k) {
        int it = t + k * NTHREADS;
        int j  = it >> 4;            // position within row
        int q  = (it & 15) << 2;     // float offset within the 64-dim vector
        int vs = src_ids[row * SEQ + j];
        int vd = dst_ids[row * SEQ + j];
        float4 r1 = *(const float4*)&enc[vs][q];
        float4 r2 = *(const float4*)&enc[vd][q];
        out4[rowOff + it]          = r1;
        out4[dstOff + rowOff + it] = r2;
    }
}

extern "C" void kernel_launch(void* const* d_in, const int* in_sizes, int n_in,
                              void* d_out, int out_size, void* d_ws, size_t ws_size,
                              hipStream_t stream) {
    const int*   src = (const int*)d_in[0];
    const int*   dst = (const int*)d_in[1];
    const float* W1  = (const float*)d_in[2];
    const float* b1  = (const float*)d_in[3];
    const float* W2  = (const float*)d_in[4];
    const float* b2  = (const float*)d_in[5];
    ncoe_kernel<<<BATCH, NTHREADS, 0, stream>>>(src, dst, W1, b1, W2, b2, (float*)d_out);
}